// Round 2
// baseline (484.219 us; speedup 1.0000x reference)
//
#include <hip/hip_runtime.h>

#define VERTS    100000
#define NCLUST   25000
#define BATCH_N  1024
#define THREADS  1024
#define RPB      4                        // rows per persistent block
#define NBLOCKS  (BATCH_N / RPB)          // 256 = one block per CU
#define NC4      (NCLUST / 4)             // 6250 float4 per x row
#define NV4      (VERTS / 4)              // 25000 float4 per out row
#define NSTG     7                        // ceil(NC4 / THREADS)
#define NCHUNK   6                        // 6 chunks x 4 iters = 24 full iters
#define TAILQ    (NV4 - NCHUNK * 4 * THREADS)  // 424 remainder elements

typedef float  f32x4 __attribute__((ext_vector_type(4)));
typedef int    i32x4 __attribute__((ext_vector_type(4)));

// out[b, v] = x[b, v2c[v]]
// Persistent: 256 blocks, each owns 4 consecutive batch rows.
// Row r+1 is prefetched into REGISTERS (static-indexed, stays in VGPRs) while
// row r's gather+store stream runs; ds_write at the row boundary. Inside the
// gather, idx loads for chunk c+1 are issued BEFORE chunk c's stores so the
// in-order vmcnt drain for the idx never has to retire a pending HBM store.
__global__ __launch_bounds__(THREADS) void gather_pipe_kernel(
    const float* __restrict__ x,     // [BATCH_N, NCLUST]
    const int*   __restrict__ v2c,   // [VERTS]
    float*       __restrict__ out)   // [BATCH_N, VERTS]
{
    extern __shared__ float lds[];   // NCLUST floats = 100000 B -> 1 block/CU
    const int tid  = threadIdx.x;
    const int row0 = blockIdx.x * RPB;

    const i32x4* __restrict__ v2c4 = reinterpret_cast<const i32x4*>(v2c);

    // ---- prologue: stage row0 into registers (7 x float4 = 28 VGPRs) ----
    f32x4 stage[NSTG];
    {
        const f32x4* __restrict__ xr =
            reinterpret_cast<const f32x4*>(x + (size_t)row0 * NCLUST);
        #pragma unroll
        for (int k = 0; k < NSTG; ++k) {
            const int i = tid + k * THREADS;
            if (k < NSTG - 1 || i < NC4)
                stage[k] = __builtin_nontemporal_load(&xr[i]);
        }
    }

    for (int r = 0; r < RPB; ++r) {
        // ---- commit staged row r to LDS ----
        f32x4* lds4 = reinterpret_cast<f32x4*>(lds);
        #pragma unroll
        for (int k = 0; k < NSTG; ++k) {
            const int i = tid + k * THREADS;
            if (k < NSTG - 1 || i < NC4) lds4[i] = stage[k];
        }
        __syncthreads();

        const bool more = (r + 1 < RPB);
        // clamped: never forms an out-of-range row pointer (only read if more)
        const int rn = more ? (row0 + r + 1) : row0;
        const f32x4* __restrict__ xn =
            reinterpret_cast<const f32x4*>(x + (size_t)rn * NCLUST);
        f32x4* __restrict__ out4 = reinterpret_cast<f32x4*>(
            out + (size_t)(row0 + r) * VERTS);

        // ---- pipelined gather over 24 strided iterations + 424-elem tail ----
        i32x4 id[4];
        #pragma unroll
        for (int k = 0; k < 4; ++k) id[k] = v2c4[tid + k * THREADS];

        #pragma unroll
        for (int c = 0; c < NCHUNK; ++c) {
            // (1) idx prefetch for chunk c+1 — issued before this chunk's stores
            i32x4 idn[4];
            if (c + 1 < NCHUNK) {
                #pragma unroll
                for (int k = 0; k < 4; ++k)
                    idn[k] = v2c4[tid + ((c + 1) * 4 + k) * THREADS];
            }
            // (2) next-row register prefetch, spread across the chunks so the
            //     HBM reads hide under the store stream (async-STAGE split)
            if (more) {
                if (c < NSTG - 1)   // c = 0..5 -> stage[0..5], static index
                    stage[c] = __builtin_nontemporal_load(&xn[tid + c * THREADS]);
                if (c == NCHUNK - 1) {
                    const int i = tid + (NSTG - 1) * THREADS;
                    if (i < NC4)
                        stage[NSTG - 1] = __builtin_nontemporal_load(&xn[i]);
                }
            }
            // (3) LDS gather + streaming store for chunk c
            #pragma unroll
            for (int k = 0; k < 4; ++k) {
                const i32x4 ix = id[k];
                f32x4 o;
                o.x = lds[ix.x];
                o.y = lds[ix.y];
                o.z = lds[ix.z];
                o.w = lds[ix.w];
                __builtin_nontemporal_store(o, &out4[tid + (c * 4 + k) * THREADS]);
            }
            // (4) rotate the idx pipeline (static indices, stays in VGPRs)
            if (c + 1 < NCHUNK) {
                #pragma unroll
                for (int k = 0; k < 4; ++k) id[k] = idn[k];
            }
        }
        if (tid < TAILQ) {
            const int q = tid + NCHUNK * 4 * THREADS;
            const i32x4 ix = v2c4[q];
            f32x4 o;
            o.x = lds[ix.x];
            o.y = lds[ix.y];
            o.z = lds[ix.z];
            o.w = lds[ix.w];
            __builtin_nontemporal_store(o, &out4[q]);
        }
        __syncthreads();   // row r gather done -> LDS safe to overwrite
    }
}

extern "C" void kernel_launch(void* const* d_in, const int* in_sizes, int n_in,
                              void* d_out, int out_size, void* d_ws, size_t ws_size,
                              hipStream_t stream) {
    const float* x   = (const float*)d_in[0];   // [1024, 25000] f32
    const int*   v2c = (const int*)d_in[1];     // [100000] i32
    float*       out = (float*)d_out;           // [1024, 100000] f32

    const int lds_bytes = NCLUST * (int)sizeof(float);  // 100000 B
    static bool attr_set = false;  // idempotent host-side attribute, not a stream op
    if (!attr_set) {
        hipFuncSetAttribute(reinterpret_cast<const void*>(gather_pipe_kernel),
                            hipFuncAttributeMaxDynamicSharedMemorySize, lds_bytes);
        attr_set = true;
    }

    gather_pipe_kernel<<<NBLOCKS, THREADS, lds_bytes, stream>>>(x, v2c, out);
}